// Round 1
// baseline (309.502 us; speedup 1.0000x reference)
//
#include <hip/hip_runtime.h>

// PadWithin: out[b,c,2i,2j] = feats[b,c,i,j], all other entries zero.
// feats: (16,64,128,128) fp32 -> out: (16,64,256,256) fp32.
// Pure streaming memory movement: 64 MiB read + 256 MiB write (full output
// must be written — harness re-poisons d_out with 0xAA each call).
//
// Structure: one wave per input row ("row-pair" of the output). The pair
// (rows 2i, 2i+1) is a contiguous 2 KiB span of the output:
//   lane stores expanded float4 at [lane] and zero float4 at [64+lane].
// Grid-stride loop with a capped grid (2048 blocks = 256 CU x 8 blocks of
// 256 thr = full occupancy) gives each wave 16 independent iterations ->
// many loads/stores in flight per thread instead of one-shot threads.
// Nontemporal hints: data is streamed exactly once, keep it out of L2.

#define IN_W   128
#define PAIRS  (16 * 64 * 128)   // B*C*IN_H input rows == output row-pairs

typedef float f2 __attribute__((ext_vector_type(2)));
typedef float f4 __attribute__((ext_vector_type(4)));

__global__ __launch_bounds__(256) void pad_within_kernel(
    const float* __restrict__ in, float* __restrict__ out) {
    const unsigned lane = threadIdx.x & 63u;                          // 0..63
    const unsigned wid  = (blockIdx.x * blockDim.x + threadIdx.x) >> 6;
    const unsigned nw   = (gridDim.x * blockDim.x) >> 6;              // total waves

    const f4 zero = {0.f, 0.f, 0.f, 0.f};

    #pragma unroll 4
    for (unsigned p = wid; p < PAIRS; p += nw) {
        // Input row p: 128 floats; lane reads float2 -> 512 B/wave, coalesced.
        const f2* irow = (const f2*)(in + (size_t)p * IN_W);
        f2 x = __builtin_nontemporal_load(&irow[lane]);

        f4 val = {x.x, 0.f, x.y, 0.f};

        // Output rows 2p (data+zeros interleaved) and 2p+1 (all zeros):
        // contiguous 512 floats = 128 float4s starting at p*512.
        f4* opair = (f4*)(out + (size_t)p * 512);
        __builtin_nontemporal_store(val,  &opair[lane]);        // even row
        __builtin_nontemporal_store(zero, &opair[64u + lane]);  // odd row
    }
}

extern "C" void kernel_launch(void* const* d_in, const int* in_sizes, int n_in,
                              void* d_out, int out_size, void* d_ws, size_t ws_size,
                              hipStream_t stream) {
    const float* feats = (const float*)d_in[0];
    float* out = (float*)d_out;
    // 2048 blocks x 256 threads = 524288 threads = 8192 waves;
    // PAIRS/8192 = 16 grid-stride iterations per wave, no tail.
    dim3 block(256);
    dim3 grid(2048);
    pad_within_kernel<<<grid, block, 0, stream>>>(feats, out);
}